// Round 7
// baseline (176.671 us; speedup 1.0000x reference)
//
#include <hip/hip_runtime.h>
#include <math.h>

// FC-CapsNet routing: u[128,1152,8], W[1152,32,8,16], b[1152,32] -> v[128,32,16]
// R7: BB=8 (halves LDS-read cost/batch, proven R5) + grid (288,4)=1152 blocks
// (4.5 blocks/CU, the occupancy R5 lacked) + global_load_lds staging into an
// EXACTLY-LINEAR-read LDS layout [n][s][lane]: lane l reads 16B at
// n*2048 + s*1024 + l*16 (consecutive per lane -> conflict-free under any
// phasing). Global source is per-lane permuted (G21: linear LDS dest,
// permuted src). Softmax = proven __shfl_xor max-free chain.
// NOTE (profiling): dur_us includes fixed ~50us harness cost (256MiB d_ws
// 0xAA poison fill ~45us + d_in restore) visible as fillBufferAligned rows.

#define NB 128
#define NI 1152
#define NJ 32
#define DM 16
#define JMSZ 512            // NJ*DM
#define BB 8                // batches register-blocked per wave
#define TPB 256
#define BPB 32              // (TPB/64)*BB batches per block

// ---------------- W tile staging (global_load_lds, linear LDS) ---------
// LDS layout: slot16 = n*128 + s*64 + l  (l = 2j+h), i.e. LDS byte
// x = n*2048 + s*1024 + l*16 holds global tile byte
// g = j*512 + n*64 + h*32 + s*16. Staging: wave (q,wid) covers 64
// consecutive slots (n,s uniform); lane supplies the permuted global src,
// HW writes LDS base + lane*16 (linear) — exactly global_load_lds's fanout.
__device__ __forceinline__ void stageW(float* dstLds, const float* src,
                                       int wid, int lane) {
#pragma unroll
  for (int q = 0; q < 4; ++q) {
    const int slotbase = q * 256 + wid * 64;   // wave-uniform, 64-aligned
    const int ns = slotbase >> 6;              // = 4q + wid
    const int n = ns >> 1, s = ns & 1;
    const int g = (lane >> 1) * 512 + n * 64 + (lane & 1) * 32 + s * 16;
    __builtin_amdgcn_global_load_lds((const char*)src + g,
                                     (char*)dstLds + slotbase * 16, 16, 0, 0);
  }
}

template <int IC_, bool ATOMIC>
__global__ __launch_bounds__(TPB, 4) void caps_main(
    const float* __restrict__ u, const float* __restrict__ W,
    const float* __restrict__ bias, float* __restrict__ out, int nchunk) {
  __shared__ __align__(16) float wl[2][4096];

  const int chunk = blockIdx.x;
  const int bg = blockIdx.y;
  const int tid = threadIdx.x;
  const int wid = __builtin_amdgcn_readfirstlane(tid >> 6);
  const int lane = tid & 63;
  const int j = lane >> 1;                    // parent capsule 0..31
  const int h = lane & 1;                     // m-octet
  const int b0 = __builtin_amdgcn_readfirstlane(bg * BPB + wid * BB);
  const int i0 = chunk * IC_;

  stageW(wl[0], W + (size_t)i0 * 4096, wid, lane);

  float acc[BB][8];
#pragma unroll
  for (int bb = 0; bb < BB; ++bb)
#pragma unroll
    for (int k = 0; k < 8; ++k) acc[bb][k] = 0.f;

  __syncthreads();                            // tile 0 resident (vmcnt drain)

  for (int t = 0; t < IC_; ++t) {
    const int i = i0 + t;
    if (t + 1 < IC_) stageW(wl[(t + 1) & 1], W + (size_t)(i + 1) * 4096, wid, lane);
    const char* wb = (const char*)wl[t & 1];

    float un[BB][8];                          // wave-uniform -> scalar loads
#pragma unroll
    for (int bb = 0; bb < BB; ++bb) {
      const float* up = u + ((size_t)(b0 + bb) * NI + i) * 8;
      float4 a0 = *(const float4*)up;
      float4 a1 = *(const float4*)(up + 4);
      un[bb][0] = a0.x; un[bb][1] = a0.y; un[bb][2] = a0.z; un[bb][3] = a0.w;
      un[bb][4] = a1.x; un[bb][5] = a1.y; un[bb][6] = a1.z; un[bb][7] = a1.w;
    }
    const float bj = bias[(size_t)i * NJ + j];

    float uh[BB][8];
#pragma unroll
    for (int bb = 0; bb < BB; ++bb)
#pragma unroll
      for (int k = 0; k < 8; ++k) uh[bb][k] = 0.f;

#pragma unroll
    for (int n = 0; n < 8; ++n) {
      // linear-lane reads: conflict-free (consecutive 16B per lane)
      float4 w0 = *(const float4*)(wb + n * 2048 + lane * 16);
      float4 w1 = *(const float4*)(wb + n * 2048 + 1024 + lane * 16);
#pragma unroll
      for (int bb = 0; bb < BB; ++bb) {
        const float uv = un[bb][n];
        uh[bb][0] = fmaf(uv, w0.x, uh[bb][0]);
        uh[bb][1] = fmaf(uv, w0.y, uh[bb][1]);
        uh[bb][2] = fmaf(uv, w0.z, uh[bb][2]);
        uh[bb][3] = fmaf(uv, w0.w, uh[bb][3]);
        uh[bb][4] = fmaf(uv, w1.x, uh[bb][4]);
        uh[bb][5] = fmaf(uv, w1.y, uh[bb][5]);
        uh[bb][6] = fmaf(uv, w1.z, uh[bb][6]);
        uh[bb][7] = fmaf(uv, w1.w, uh[bb][7]);
      }
    }

    // agreement + MAX-FREE softmax over j (a = |uh|^2/4 bounded; f32-safe)
    // lane = 2j+h: xor1 combines octets; xor2..32 sum over the 32 j.
#pragma unroll
    for (int bb = 0; bb < BB; ++bb) {
      float s2 = uh[bb][0] * uh[bb][0] + uh[bb][1] * uh[bb][1] +
                 uh[bb][2] * uh[bb][2] + uh[bb][3] * uh[bb][3] +
                 uh[bb][4] * uh[bb][4] + uh[bb][5] * uh[bb][5] +
                 uh[bb][6] * uh[bb][6] + uh[bb][7] * uh[bb][7];
      s2 += __shfl_xor(s2, 1);                // full |u_hat|^2 (both octets)
      const float e = __expf(s2 * 0.25f);     // a = s2/sqrt(16); no max
      float es = e;
      es += __shfl_xor(es, 2);
      es += __shfl_xor(es, 4);
      es += __shfl_xor(es, 8);
      es += __shfl_xor(es, 16);
      es += __shfl_xor(es, 32);               // sum over all 32 j
      const float c = e * __builtin_amdgcn_rcpf(es) + bj;
#pragma unroll
      for (int k = 0; k < 8; ++k) acc[bb][k] = fmaf(c, uh[bb][k], acc[bb][k]);
    }

    __syncthreads();  // next tile resident; all reads of wb done
  }

#pragma unroll
  for (int bb = 0; bb < BB; ++bb) {
    if (ATOMIC) {
      float* p = out + (size_t)(b0 + bb) * JMSZ + j * DM + h * 8;
#pragma unroll
      for (int k = 0; k < 8; ++k) atomicAdd(p + k, acc[bb][k]);
    } else {
      float* p = out + ((size_t)(b0 + bb) * nchunk + chunk) * JMSZ + j * DM + h * 8;
      *(float4*)p = make_float4(acc[bb][0], acc[bb][1], acc[bb][2], acc[bb][3]);
      *(float4*)(p + 4) = make_float4(acc[bb][4], acc[bb][5], acc[bb][6], acc[bb][7]);
    }
  }
}

// Reduce chunk partials + squash, coalesced (proven R6). Wave layout:
// q = lane>>3 (8 chunk-slices), r = lane&7 (8 consecutive float4s). Each
// thread sums NSUM/8 float4s at stride 2KB; q-combine via xor8/16/32;
// m-norm: 4 comps in-lane + xor1/xor2 over mq lanes.
template <int NSUM>
__global__ __launch_bounds__(256) void caps_fin(const float* __restrict__ part,
                                                float* __restrict__ v) {
  if constexpr (NSUM == 1) {
    const int o = blockIdx.x * 256 + threadIdx.x;   // b*512 + j*16 + m
    const float s = part[o];
    float sq = s * s;                               // m = lane bits 0..3
    sq += __shfl_xor(sq, 1);
    sq += __shfl_xor(sq, 2);
    sq += __shfl_xor(sq, 4);
    sq += __shfl_xor(sq, 8);
    const float nrm = sqrtf(sq);
    v[o] = (sq / (1.0f + sq)) / (nrm + 1e-20f) * s;
  } else {
    constexpr int QC = NSUM / 8;
    const int lane = threadIdx.x & 63;
    const int wv = (blockIdx.x * 256 + threadIdx.x) >> 6;  // global wave id
    const int q = lane >> 3;
    const int r = lane & 7;
    const int F = wv * 8 + r;                  // float4 id: b*128 + j*4 + mq
    const int b = F >> 7;
    const int jm4 = F & 127;
    const float* p = part + (size_t)b * NSUM * JMSZ + (size_t)q * QC * JMSZ + jm4 * 4;
    float4 s4 = make_float4(0.f, 0.f, 0.f, 0.f);
#pragma unroll 4
    for (int cc = 0; cc < QC; ++cc) {
      float4 x = *(const float4*)(p + (size_t)cc * JMSZ);
      s4.x += x.x; s4.y += x.y; s4.z += x.z; s4.w += x.w;
    }
#pragma unroll
    for (int mask = 8; mask <= 32; mask <<= 1) {   // combine 8 q-slices
      s4.x += __shfl_xor(s4.x, mask);
      s4.y += __shfl_xor(s4.y, mask);
      s4.z += __shfl_xor(s4.z, mask);
      s4.w += __shfl_xor(s4.w, mask);
    }
    float sq = s4.x * s4.x + s4.y * s4.y + s4.z * s4.z + s4.w * s4.w;
    sq += __shfl_xor(sq, 1);                   // mq bit0
    sq += __shfl_xor(sq, 2);                   // mq bit1
    const float nrm = sqrtf(sq);
    const float f = (sq / (1.0f + sq)) / (nrm + 1e-20f);
    if (q == 0)
      *(float4*)(v + (size_t)F * 4) = make_float4(f * s4.x, f * s4.y, f * s4.z, f * s4.w);
  }
}

extern "C" void kernel_launch(void* const* d_in, const int* in_sizes, int n_in,
                              void* d_out, int out_size, void* d_ws, size_t ws_size,
                              hipStream_t stream) {
  const float* u = (const float*)d_in[0];
  const float* W = (const float*)d_in[1];
  const float* bias = (const float*)d_in[2];
  float* out = (float*)d_out;

  const size_t P288 = (size_t)NB * 288 * JMSZ * sizeof(float);  // 75.5 MB
  const size_t P64 = (size_t)NB * 64 * JMSZ * sizeof(float);    // 16 MB

  if (ws_size >= P288) {
    // 1152 blocks of 256 thr (BB=8), 32KB LDS -> 4+ blocks/CU resident
    float* part = (float*)d_ws;
    caps_main<4, false><<<dim3(288, NB / BPB), TPB, 0, stream>>>(u, W, bias, part, 288);
    caps_fin<288><<<512, 256, 0, stream>>>(part, out);
  } else if (ws_size >= P64) {
    float* part = (float*)d_ws;
    caps_main<18, false><<<dim3(64, NB / BPB), TPB, 0, stream>>>(u, W, bias, part, 64);
    caps_fin<64><<<512, 256, 0, stream>>>(part, out);
  } else {
    float* sbuf = (float*)d_ws;
    hipMemsetAsync(sbuf, 0, (size_t)NB * JMSZ * sizeof(float), stream);
    caps_main<18, true><<<dim3(64, NB / BPB), TPB, 0, stream>>>(u, W, bias, sbuf, 64);
    caps_fin<1><<<(NB * JMSZ) / 256, 256, 0, stream>>>(sbuf, out);
  }
}

// Round 8
// 102.662 us; speedup vs baseline: 1.7209x; 1.7209x over previous
//
#include <hip/hip_runtime.h>
#include <math.h>

// FC-CapsNet routing: u[128,1152,8], W[1152,32,8,16], b[1152,32] -> v[128,32,16]
// R8: NO LDS W-tile, NO barriers. W read directly from global (L2-resident:
// grid (128,4) with 128%8==0 puts all 4 batch-groups of a chunk on one XCD
// -> 2.3 MB unique W per XCD L2). Wave reads are 2KB-contiguous per n
// (lane=2j+h reads W[i][j][n][h*8..h*8+7]). Waves free-run: the per-t
// __syncthreads + ds_read latency chains that capped R5-R7 at 25-33%
// VALUBusy are gone. BB=8 batches/wave; partials 32 MB (<= L2 aggregate,
// avoids R7's write-allocate thrash: 75MB partials -> 238MB WRITE).
// NOTE (profiling): dur_us includes fixed ~50us harness cost (256MiB d_ws
// 0xAA poison fill ~45us + d_in restore) visible as fillBufferAligned rows.

#define NB 128
#define NI 1152
#define NJ 32
#define DM 16
#define JMSZ 512            // NJ*DM
#define BB 8                // batches register-blocked per wave
#define TPB 256
#define BPB ((TPB / 64) * BB)  // 32 batches per block

template <int IC_, bool ATOMIC>
__global__ __launch_bounds__(TPB, 2) void caps_main(
    const float* __restrict__ u, const float* __restrict__ W,
    const float* __restrict__ bias, float* __restrict__ out, int nchunk) {
  const int chunk = blockIdx.x;
  const int bg = blockIdx.y;
  const int tid = threadIdx.x;
  const int wid = __builtin_amdgcn_readfirstlane(tid >> 6);
  const int lane = tid & 63;
  const int j = lane >> 1;                    // parent capsule 0..31
  const int h = lane & 1;                     // m-octet
  const int b0 = __builtin_amdgcn_readfirstlane(bg * BPB + wid * BB);
  const int i0 = chunk * IC_;

  float acc[BB][8];
#pragma unroll
  for (int bb = 0; bb < BB; ++bb)
#pragma unroll
    for (int k = 0; k < 8; ++k) acc[bb][k] = 0.f;

  // per-lane W base for this (j,h): byte offset j*512 + h*32 within a tile
  const char* wbase = (const char*)W + (size_t)i0 * 16384 + j * 512 + h * 32;

  for (int t = 0; t < IC_; ++t) {
    const int i = i0 + t;
    const char* wp = wbase + (size_t)t * 16384;

    float un[BB][8];                          // wave-uniform -> scalar loads
#pragma unroll
    for (int bb = 0; bb < BB; ++bb) {
      const float* up = u + ((size_t)(b0 + bb) * NI + i) * 8;
      float4 a0 = *(const float4*)up;
      float4 a1 = *(const float4*)(up + 4);
      un[bb][0] = a0.x; un[bb][1] = a0.y; un[bb][2] = a0.z; un[bb][3] = a0.w;
      un[bb][4] = a1.x; un[bb][5] = a1.y; un[bb][6] = a1.z; un[bb][7] = a1.w;
    }
    const float bj = bias[(size_t)i * NJ + j];

    // W loads: 16 independent b128, coalesced (wave covers 2KB per n)
    float4 w0[8], w1[8];
#pragma unroll
    for (int n = 0; n < 8; ++n) {
      w0[n] = *(const float4*)(wp + n * 64);
      w1[n] = *(const float4*)(wp + n * 64 + 16);
    }

    float uh[BB][8];
#pragma unroll
    for (int bb = 0; bb < BB; ++bb)
#pragma unroll
      for (int k = 0; k < 8; ++k) uh[bb][k] = 0.f;

#pragma unroll
    for (int n = 0; n < 8; ++n) {
#pragma unroll
      for (int bb = 0; bb < BB; ++bb) {
        const float uv = un[bb][n];
        uh[bb][0] = fmaf(uv, w0[n].x, uh[bb][0]);
        uh[bb][1] = fmaf(uv, w0[n].y, uh[bb][1]);
        uh[bb][2] = fmaf(uv, w0[n].z, uh[bb][2]);
        uh[bb][3] = fmaf(uv, w0[n].w, uh[bb][3]);
        uh[bb][4] = fmaf(uv, w1[n].x, uh[bb][4]);
        uh[bb][5] = fmaf(uv, w1[n].y, uh[bb][5]);
        uh[bb][6] = fmaf(uv, w1[n].z, uh[bb][6]);
        uh[bb][7] = fmaf(uv, w1[n].w, uh[bb][7]);
      }
    }

    // agreement + MAX-FREE softmax over j (a = |uh|^2/4 bounded; f32-safe)
    // lane = 2j+h: xor1 combines octets; xor2..32 sum over the 32 j.
    // 8 independent 6-op shuffle chains (one per bb) -> good ILP.
#pragma unroll
    for (int bb = 0; bb < BB; ++bb) {
      float s2 = uh[bb][0] * uh[bb][0] + uh[bb][1] * uh[bb][1] +
                 uh[bb][2] * uh[bb][2] + uh[bb][3] * uh[bb][3] +
                 uh[bb][4] * uh[bb][4] + uh[bb][5] * uh[bb][5] +
                 uh[bb][6] * uh[bb][6] + uh[bb][7] * uh[bb][7];
      s2 += __shfl_xor(s2, 1);                // full |u_hat|^2 (both octets)
      const float e = __expf(s2 * 0.25f);     // a = s2/sqrt(16); no max
      float es = e;
      es += __shfl_xor(es, 2);
      es += __shfl_xor(es, 4);
      es += __shfl_xor(es, 8);
      es += __shfl_xor(es, 16);
      es += __shfl_xor(es, 32);               // sum over all 32 j
      const float c = e * __builtin_amdgcn_rcpf(es) + bj;
#pragma unroll
      for (int k = 0; k < 8; ++k) acc[bb][k] = fmaf(c, uh[bb][k], acc[bb][k]);
    }
  }

#pragma unroll
  for (int bb = 0; bb < BB; ++bb) {
    if (ATOMIC) {
      float* p = out + (size_t)(b0 + bb) * JMSZ + j * DM + h * 8;
#pragma unroll
      for (int k = 0; k < 8; ++k) atomicAdd(p + k, acc[bb][k]);
    } else {
      float* p = out + ((size_t)(b0 + bb) * nchunk + chunk) * JMSZ + j * DM + h * 8;
      *(float4*)p = make_float4(acc[bb][0], acc[bb][1], acc[bb][2], acc[bb][3]);
      *(float4*)(p + 4) = make_float4(acc[bb][4], acc[bb][5], acc[bb][6], acc[bb][7]);
    }
  }
}

// Reduce chunk partials + squash, coalesced (proven R6/R7). Wave layout:
// q = lane>>3 (8 chunk-slices), r = lane&7 (8 consecutive float4s). Each
// thread sums NSUM/8 float4s at stride 2KB; q-combine via xor8/16/32;
// m-norm: 4 comps in-lane + xor1/xor2 over mq lanes.
template <int NSUM>
__global__ __launch_bounds__(256) void caps_fin(const float* __restrict__ part,
                                                float* __restrict__ v) {
  if constexpr (NSUM == 1) {
    const int o = blockIdx.x * 256 + threadIdx.x;   // b*512 + j*16 + m
    const float s = part[o];
    float sq = s * s;                               // m = lane bits 0..3
    sq += __shfl_xor(sq, 1);
    sq += __shfl_xor(sq, 2);
    sq += __shfl_xor(sq, 4);
    sq += __shfl_xor(sq, 8);
    const float nrm = sqrtf(sq);
    v[o] = (sq / (1.0f + sq)) / (nrm + 1e-20f) * s;
  } else {
    constexpr int QC = NSUM / 8;
    const int lane = threadIdx.x & 63;
    const int wv = (blockIdx.x * 256 + threadIdx.x) >> 6;  // global wave id
    const int q = lane >> 3;
    const int r = lane & 7;
    const int F = wv * 8 + r;                  // float4 id: b*128 + j*4 + mq
    const int b = F >> 7;
    const int jm4 = F & 127;
    const float* p = part + (size_t)b * NSUM * JMSZ + (size_t)q * QC * JMSZ + jm4 * 4;
    float4 s4 = make_float4(0.f, 0.f, 0.f, 0.f);
#pragma unroll 4
    for (int cc = 0; cc < QC; ++cc) {
      float4 x = *(const float4*)(p + (size_t)cc * JMSZ);
      s4.x += x.x; s4.y += x.y; s4.z += x.z; s4.w += x.w;
    }
#pragma unroll
    for (int mask = 8; mask <= 32; mask <<= 1) {   // combine 8 q-slices
      s4.x += __shfl_xor(s4.x, mask);
      s4.y += __shfl_xor(s4.y, mask);
      s4.z += __shfl_xor(s4.z, mask);
      s4.w += __shfl_xor(s4.w, mask);
    }
    float sq = s4.x * s4.x + s4.y * s4.y + s4.z * s4.z + s4.w * s4.w;
    sq += __shfl_xor(sq, 1);                   // mq bit0
    sq += __shfl_xor(sq, 2);                   // mq bit1
    const float nrm = sqrtf(sq);
    const float f = (sq / (1.0f + sq)) / (nrm + 1e-20f);
    if (q == 0)
      *(float4*)(v + (size_t)F * 4) = make_float4(f * s4.x, f * s4.y, f * s4.z, f * s4.w);
  }
}

extern "C" void kernel_launch(void* const* d_in, const int* in_sizes, int n_in,
                              void* d_out, int out_size, void* d_ws, size_t ws_size,
                              hipStream_t stream) {
  const float* u = (const float*)d_in[0];
  const float* W = (const float*)d_in[1];
  const float* bias = (const float*)d_in[2];
  float* out = (float*)d_out;

  const size_t P128 = (size_t)NB * 128 * JMSZ * sizeof(float);  // 32 MB
  const size_t P64 = (size_t)NB * 64 * JMSZ * sizeof(float);    // 16 MB

  if (ws_size >= P128) {
    // grid (128,4)=512 blocks of 256 thr, no LDS -> 2 blocks/CU, 8 waves/CU.
    // 128%8==0: all 4 bg of a chunk share an XCD -> W L2-resident (2.3MB/XCD).
    float* part = (float*)d_ws;
    caps_main<9, false><<<dim3(128, NB / BPB), TPB, 0, stream>>>(u, W, bias, part, 128);
    caps_fin<128><<<512, 256, 0, stream>>>(part, out);
  } else if (ws_size >= P64) {
    float* part = (float*)d_ws;
    caps_main<18, false><<<dim3(64, NB / BPB), TPB, 0, stream>>>(u, W, bias, part, 64);
    caps_fin<64><<<512, 256, 0, stream>>>(part, out);
  } else {
    float* sbuf = (float*)d_ws;
    hipMemsetAsync(sbuf, 0, (size_t)NB * JMSZ * sizeof(float), stream);
    caps_main<18, true><<<dim3(64, NB / BPB), TPB, 0, stream>>>(u, W, bias, sbuf, 64);
    caps_fin<1><<<(NB * JMSZ) / 256, 256, 0, stream>>>(sbuf, out);
  }
}